// Round 16
// baseline (135.830 us; speedup 1.0000x reference)
//
#include <hip/hip_runtime.h>
#include <hip/hip_bf16.h>

#define SEQ 4096
#define HID 768
#define NHEAD 12
#define HDIM 64
#define KVB 64
#define NT (SEQ / KVB)   // 64
#define PBK 64
#define PNT (HID / PBK)  // 12

typedef __attribute__((ext_vector_type(8))) short bf16x8;
typedef __attribute__((ext_vector_type(4))) float f32x4;
typedef __attribute__((ext_vector_type(4))) short s16x4;

static __device__ __forceinline__ short f2bf(float f) {
    unsigned u = __builtin_bit_cast(unsigned, f);
    unsigned r = (u + 0x7fffu + ((u >> 16) & 1u)) >> 16;
    return (short)r;
}
static __device__ __forceinline__ unsigned cvtpk(float lo, float hi) {
    unsigned r;
    asm("v_cvt_pk_bf16_f32 %0, %1, %2" : "=v"(r) : "v"(lo), "v"(hi));
    return r;
}
static __device__ __forceinline__ float max3f(float a, float b, float c) {
    float r;
    asm("v_max3_f32 %0, %1, %2, %3" : "=v"(r) : "v"(a), "v"(b), "v"(c));
    return r;
}
static __device__ __forceinline__ void glds16(const void* g, void* l) {
    __builtin_amdgcn_global_load_lds(
        (const __attribute__((address_space(1))) unsigned*)g,
        (__attribute__((address_space(3))) unsigned*)l, 16, 0, 0);
}

// ---------------------------------------------------------------------------
// Merged fp32 -> bf16 cast for hs + Wq/Wk/Wv, plus mask*log2e (f32) prep.
// Unit = 8 elements. hs: 393216; each W: 73728; mask: 512. Grid 2402x256.
// ---------------------------------------------------------------------------
__global__ __launch_bounds__(256) void cast_all_kernel(
    const float* __restrict__ hs, const float* __restrict__ Wq,
    const float* __restrict__ Wk, const float* __restrict__ Wv,
    const float* __restrict__ mask,
    short* __restrict__ hsb, short* __restrict__ Wb,
    float* __restrict__ maskML)
{
    const float ML = 1.44269504088896340736f;
    const size_t i = (size_t)blockIdx.x * 256 + threadIdx.x;
    if (i >= 614400) {                       // mask path (f32 out, scaled)
        const size_t j = i - 614400;         // 0..511
        const float4* sp = reinterpret_cast<const float4*>(mask) + j * 2;
        float4 a = sp[0], b = sp[1];
        a.x *= ML; a.y *= ML; a.z *= ML; a.w *= ML;
        b.x *= ML; b.y *= ML; b.z *= ML; b.w *= ML;
        float4* dp = reinterpret_cast<float4*>(maskML) + j * 2;
        dp[0] = a; dp[1] = b;
        return;
    }
    const float* s; short* d; size_t idx;
    if (i < 393216) {
        s = hs; d = hsb; idx = i;
    } else {
        size_t j = i - 393216;
        int z = (int)(j / 73728);
        idx = j - (size_t)z * 73728;
        s = (z == 0) ? Wq : ((z == 1) ? Wk : Wv);
        d = Wb + (size_t)z * HID * HID;
    }
    const float4* sp = reinterpret_cast<const float4*>(s) + idx * 2;
    const float4 a = sp[0], b = sp[1];
    bf16x8 o;
    o[0] = f2bf(a.x); o[1] = f2bf(a.y); o[2] = f2bf(a.z); o[3] = f2bf(a.w);
    o[4] = f2bf(b.x); o[5] = f2bf(b.y); o[6] = f2bf(b.z); o[7] = f2bf(b.w);
    reinterpret_cast<bf16x8*>(d)[idx] = o;
}

// ---------------------------------------------------------------------------
// QKV projection, LDS-staged. Tile 128x128, BK=64, dbuf 64KB.
// Q output pre-scaled by 0.125*log2e (folds the softmax scale).
// ---------------------------------------------------------------------------
__global__ __launch_bounds__(256) void qkv_proj_kernel(
    const short* __restrict__ hsb, const short* __restrict__ Wb,
    const float* __restrict__ bq, const float* __restrict__ bk,
    const float* __restrict__ bv,
    short* __restrict__ Qb, short* __restrict__ Kb, short* __restrict__ Vt)
{
    __shared__ __align__(16) char lds[65536];
    const int z = blockIdx.z;
    const float* bias = (z == 0) ? bq : ((z == 1) ? bk : bv);

    const int lane = threadIdx.x & 63;
    const int w    = threadIdx.x >> 6;
    const int lr = lane & 15, hi = lane >> 4;
    const int wi = w >> 1, wj = w & 1;

    const short* Ag; const short* Bg; int ar0, br0;
    if (z < 2) { Ag = Wb + (size_t)z * HID * HID; ar0 = blockIdx.x * 128;
                 Bg = hsb;                        br0 = blockIdx.y * 128; }
    else       { Ag = hsb;                        ar0 = blockIdx.y * 128;
                 Bg = Wb + (size_t)2 * HID * HID; br0 = blockIdx.x * 128; }

    const int rsub = lane >> 3;
    const int c16  = (lane & 7) ^ rsub;

    auto stage = [&](int t, int buf) {
        const int k0 = t * PBK;
#pragma unroll
        for (int c = 0; c < 4; ++c) {
            const int ch = w * 4 + c;
            const int row = ch * 8 + rsub;
            glds16(Ag + (size_t)(ar0 + row) * HID + k0 + c16 * 8,
                   lds + buf * 16384 + ch * 1024);
            glds16(Bg + (size_t)(br0 + row) * HID + k0 + c16 * 8,
                   lds + 32768 + buf * 16384 + ch * 1024);
        }
    };

    stage(0, 0);
    f32x4 acc[4][4] = {};

    for (int t = 0; t < PNT; ++t) {
        asm volatile("s_waitcnt vmcnt(0)" ::: "memory");
        __builtin_amdgcn_s_barrier();
        __builtin_amdgcn_sched_barrier(0);
        if (t + 1 < PNT) stage(t + 1, (t + 1) & 1);
        const char* LA = lds + (t & 1) * 16384;
        const char* LB = lds + 32768 + (t & 1) * 16384;
#pragma unroll
        for (int ks = 0; ks < 2; ++ks) {
            bf16x8 af[4], bf_[4];
#pragma unroll
            for (int i = 0; i < 4; ++i) {
                const int rowA = wi * 64 + i * 16 + lr;
                af[i] = *reinterpret_cast<const bf16x8*>(
                    LA + rowA * 128 + (((ks * 4 + hi) ^ (rowA & 7)) << 4));
                const int rowB = wj * 64 + i * 16 + lr;
                bf_[i] = *reinterpret_cast<const bf16x8*>(
                    LB + rowB * 128 + (((ks * 4 + hi) ^ (rowB & 7)) << 4));
            }
            __builtin_amdgcn_s_setprio(1);
#pragma unroll
            for (int ia = 0; ia < 4; ++ia)
#pragma unroll
                for (int ib = 0; ib < 4; ++ib)
                    acc[ia][ib] = __builtin_amdgcn_mfma_f32_16x16x32_bf16(
                        af[ia], bf_[ib], acc[ia][ib], 0, 0, 0);
            __builtin_amdgcn_s_setprio(0);
        }
    }

    const float SCQ = 0.125f * 1.44269504088896340736f;
    if (z < 2) {
        short* outp = (z == 0) ? Qb : Kb;
        const float sc = (z == 0) ? SCQ : 1.0f;
#pragma unroll
        for (int ia = 0; ia < 4; ++ia) {
            const int nb = ar0 + wi * 64 + ia * 16 + hi * 4;
            const float4 b4 = *reinterpret_cast<const float4*>(bias + nb);
#pragma unroll
            for (int ib = 0; ib < 4; ++ib) {
                const int m = br0 + wj * 64 + ib * 16 + lr;
                s16x4 v;
                v[0] = f2bf((acc[ia][ib][0] + b4.x) * sc);
                v[1] = f2bf((acc[ia][ib][1] + b4.y) * sc);
                v[2] = f2bf((acc[ia][ib][2] + b4.z) * sc);
                v[3] = f2bf((acc[ia][ib][3] + b4.w) * sc);
                *reinterpret_cast<s16x4*>(outp + (size_t)m * HID + nb) = v;
            }
        }
    } else {
#pragma unroll
        for (int ib = 0; ib < 4; ++ib) {
            const int n = br0 + wj * 64 + ib * 16 + lr;
            const float bb = bias[n];
#pragma unroll
            for (int ia = 0; ia < 4; ++ia) {
                const int mb = ar0 + wi * 64 + ia * 16 + hi * 4;
                s16x4 v;
                v[0] = f2bf(acc[ia][ib][0] + bb);
                v[1] = f2bf(acc[ia][ib][1] + bb);
                v[2] = f2bf(acc[ia][ib][2] + bb);
                v[3] = f2bf(acc[ia][ib][3] + bb);
                *reinterpret_cast<s16x4*>(Vt + (size_t)n * SEQ + mb) = v;
            }
        }
    }
}

// ---------------------------------------------------------------------------
// Flash attention (r13 geometry, LDS-diet): 64q blocks, 8 waves =
// (qh 4) x (kh 2), each wave 16q x 32k per tile. Mask C-init read from
// GLOBAL (pre-scaled f32, L1-resident), issued BEFORE the stage glds each
// tile so the compiler's mask-wait (vmcnt(4)) leaves the prefetch in
// flight. Cuts 2/10 LDS reads per wave-tile AND shrinks LDS to 32KB ->
// 4 blocks/CU (32 waves, thread-capped).
// Zero-shuffle P via key-permuted QK^T; per-lane deferred-max softmax.
// LDS: K dbuf 2x8KB @0, V dbuf 2x8KB @16384. 32KB.
// ---------------------------------------------------------------------------
__global__ __launch_bounds__(512) void attn_kernel(
    const short* __restrict__ Qb, const short* __restrict__ Kb,
    const short* __restrict__ Vt, const float* __restrict__ maskml,
    float* __restrict__ out)
{
    __shared__ __align__(16) char lds[32768];
    const int tid  = threadIdx.x;
    const int lane = tid & 63;
    const int w    = tid >> 6;               // 0..7
    const int lr = lane & 15, hi = lane >> 4;
    const int qh = w >> 1, kh = w & 1;       // 4 q-groups x 2 key-halves
    const int head = blockIdx.y;
    const int q0 = blockIdx.x * 64 + qh * 16;

    // ---- staging: wave w owns K-chunk w and V-chunk w (8 rows x 128B each)
    const int srow = lane >> 3;
    const int c16s = (lane & 7) ^ srow ^ ((w & 1) << 2);
    const int sofK = (w * 8 + srow) * HID + head * HDIM + c16s * 8;
    const int sofV = (head * HDIM + w * 8 + srow) * SEQ + c16s * 8;
    const short* gK = Kb;                       // advances by KVB*HID
    const short* gV = Vt;                       // advances by KVB
    char* sdK = lds + w * 1024;
    char* sdV = lds + 16384 + w * 1024;

    auto stagep = [&](int buf) {
        glds16(gK + sofK, sdK + buf * 8192);
        glds16(gV + sofV, sdV + buf * 8192);
        gK += KVB * HID; gV += KVB;
    };

    stagep(0);   // tile 0 in flight across Q load

    // ---- Q fragments (pre-scaled by 0.125*log2e at projection): 16 q-rows
    const short* qp = Qb + (size_t)(q0 + lr) * HID + head * HDIM + hi * 8;
    const bf16x8 qf0 = *reinterpret_cast<const bf16x8*>(qp);
    const bf16x8 qf1 = *reinterpret_cast<const bf16x8*>(qp + 32);

    __syncthreads();   // stage(0) visible to all waves

    // ---- K read pointers: 2 VGPR bases + immediate offsets (r13 layout)
    const int kbase = ((lr >> 2) * 8) + (lr & 3);
    const int krow0 = kh * 32 + kbase;
    const int fr0   = (krow0 & 7) ^ (((krow0 >> 3) & 1) << 2);
    const int o1    = (hi ^ fr0) << 4;
    const char* kpA = lds + krow0 * 128 + o1;          // +0/+8192 buf, +512 kg1
    const char* kpB = lds + krow0 * 128 + (o1 ^ 64);
    // V read pointer: row = dg*16+lr, slot = ((kh*4+hi)^fv)<<4, fv dg-invariant
    const int fv    = (lr & 7) ^ (((lr >> 3) & 1) << 2);
    const char* vpB = lds + 16384 + lr * 128 + (((kh * 4 + hi) ^ fv) << 4);
    const float* mptr = maskml + kh * 32 + hi * 8;     // GLOBAL mask*log2e

    f32x4 acc[4] = {};
    float m_r = -INFINITY, ls = 0.f;

    auto tile = [&](int tt, int buf) {
        asm volatile("s_waitcnt vmcnt(0)" ::: "memory");  // stage(tt) landed
        __builtin_amdgcn_s_barrier();
        __builtin_amdgcn_sched_barrier(0);
        // mask C-init (global, L1) FIRST — so its wait keeps the stage glds
        // (issued next) in flight: wait = vmcnt(4).
        const f32x4 ci0 = *reinterpret_cast<const f32x4*>(mptr);
        const f32x4 ci1 = *reinterpret_cast<const f32x4*>(mptr + 4);
        mptr += KVB;
        __builtin_amdgcn_sched_barrier(0);
        if (tt + 1 < NT) stagep(buf ^ 1);
        __builtin_amdgcn_sched_barrier(0);

        // ---- QK^T (key-permuted): lane's 8 scores = keys kh*32+hi*8+(0..7)
        const int bo = buf * 8192;
        const bf16x8 kf00 = *reinterpret_cast<const bf16x8*>(kpA + bo);
        const bf16x8 kf01 = *reinterpret_cast<const bf16x8*>(kpB + bo);
        const bf16x8 kf10 = *reinterpret_cast<const bf16x8*>(kpB + bo + 512);
        const bf16x8 kf11 = *reinterpret_cast<const bf16x8*>(kpA + bo + 512);
        f32x4 z0 = ci0, z1 = ci1;
        __builtin_amdgcn_s_setprio(1);
        z0 = __builtin_amdgcn_mfma_f32_16x16x32_bf16(kf00, qf0, z0, 0, 0, 0);
        z0 = __builtin_amdgcn_mfma_f32_16x16x32_bf16(kf01, qf1, z0, 0, 0, 0);
        z1 = __builtin_amdgcn_mfma_f32_16x16x32_bf16(kf10, qf0, z1, 0, 0, 0);
        z1 = __builtin_amdgcn_mfma_f32_16x16x32_bf16(kf11, qf1, z1, 0, 0, 0);
        __builtin_amdgcn_s_setprio(0);

        // ---- e = exp2(z - m), per-lane (no cross-lane ops in common path)
        float e0[4], e1[4];
#pragma unroll
        for (int r = 0; r < 4; ++r) {
            e0[r] = exp2f(z0[r] - m_r);
            e1[r] = exp2f(z1[r] - m_r);
        }

        // ---- per-lane violation check: any e > 2^8?
        const float pa = max3f(e0[0], e0[1], e0[2]);
        const float pb = max3f(e0[3], e1[0], e1[1]);
        const float pc = max3f(e1[2], e1[3], pa);
        const float pmax = fmaxf(pb, pc);
        if (__ballot(pmax > 256.f)) {
            // rare recovery: full cross-lane max over this q-row's 32 keys
            float t_ = fmaxf(
                max3f(z0[0], z0[1], z0[2]),
                max3f(fmaxf(z0[3], z1[0]), fmaxf(z1[1], z1[2]), z1[3]));
            t_ = fmaxf(t_, __shfl_xor(t_, 16));
            t_ = fmaxf(t_, __shfl_xor(t_, 32));
            const float newm = fmaxf(m_r, t_);
            const float sc = exp2f(fmaxf(m_r - newm, -128.f));
            ls *= sc;
#pragma unroll
            for (int dg = 0; dg < 4; ++dg) acc[dg] *= sc;
            m_r = newm;
#pragma unroll
            for (int r = 0; r < 4; ++r) {
                e0[r] = exp2f(z0[r] - newm);
                e1[r] = exp2f(z1[r] - newm);
            }
        }

        // ---- accumulate l, pack P (zero-shuffle: e's ARE the PV B-frag)
        ls += ((e0[0] + e0[1]) + (e0[2] + e0[3]))
            + ((e1[0] + e1[1]) + (e1[2] + e1[3]));
        union { unsigned u[4]; bf16x8 v; } P;
        P.u[0] = cvtpk(e0[0], e0[1]);
        P.u[1] = cvtpk(e0[2], e0[3]);
        P.u[2] = cvtpk(e1[0], e1[1]);
        P.u[3] = cvtpk(e1[2], e1[3]);

        // ---- PV: O[d][q] += V[d][k]·P[k][q] over this wave's 32 keys
        __builtin_amdgcn_s_setprio(1);
#pragma unroll
        for (int dg = 0; dg < 4; ++dg) {
            const bf16x8 vf = *reinterpret_cast<const bf16x8*>(
                vpB + bo + dg * 2048);
            acc[dg] = __builtin_amdgcn_mfma_f32_16x16x32_bf16(vf, P.v, acc[dg], 0, 0, 0);
        }
        __builtin_amdgcn_s_setprio(0);
    };

#pragma unroll 1
    for (int t = 0; t < NT; t += 2) {
        tile(t, 0);
        tile(t + 1, 1);
    }

    // ---- reduce l across hi-groups
    ls += __shfl_xor(ls, 16);
    ls += __shfl_xor(ls, 32);

    // ---- flash-merge the two key-halves through LDS (overlay K/V buffers)
    __syncthreads();
    float* mg  = (float*)lds;                 // [qh][dg][lane] f32x4 = 16KB
    float* mlb = (float*)(lds + 16384);       // [qh][lane] float2 = 2KB
    if (kh == 1) {
        float2 v0; v0.x = m_r; v0.y = ls;
        *reinterpret_cast<float2*>(mlb + (qh * 64 + lane) * 2) = v0;
#pragma unroll
        for (int dg = 0; dg < 4; ++dg)
            *reinterpret_cast<f32x4*>(
                mg + ((qh * 4 + dg) * 64 + lane) * 4) = acc[dg];
    }
    __syncthreads();
    if (kh == 0) {
        const float2 v = *reinterpret_cast<const float2*>(
            mlb + (qh * 64 + lane) * 2);
        const float mm = fmaxf(m_r, v.x);
        const float sc0 = exp2f(fmaxf(m_r - mm, -128.f));
        const float sc1 = exp2f(fmaxf(v.x - mm, -128.f));
        const float rl = 1.0f / (ls * sc0 + v.y * sc1);
#pragma unroll
        for (int dg = 0; dg < 4; ++dg) {
            const f32x4 o1v = *reinterpret_cast<const f32x4*>(
                mg + ((qh * 4 + dg) * 64 + lane) * 4);
            const f32x4 of = (acc[dg] * sc0 + o1v * sc1) * rl;
            float* op = out + (size_t)(q0 + lr) * HID
                      + head * HDIM + dg * 16 + hi * 4;
            *reinterpret_cast<f32x4*>(op) = of;
        }
    }
}

// ---------------------------------------------------------------------------
extern "C" void kernel_launch(void* const* d_in, const int* in_sizes, int n_in,
                              void* d_out, int out_size, void* d_ws, size_t ws_size,
                              hipStream_t stream) {
    const float* hs   = (const float*)d_in[0];
    const float* mask = (const float*)d_in[1];
    const float* Wq   = (const float*)d_in[2];
    const float* bq   = (const float*)d_in[3];
    const float* Wk   = (const float*)d_in[4];
    const float* bk   = (const float*)d_in[5];
    const float* Wv   = (const float*)d_in[6];
    const float* bv   = (const float*)d_in[7];

    short* Qb = (short*)d_ws;                       // bf16 [SEQ][HID], pre-scaled
    short* Kb = Qb + (size_t)SEQ * HID;             // bf16 [SEQ][HID]
    short* Vt = Kb + (size_t)SEQ * HID;             // bf16 [HID][SEQ]
    float* maskML = (float*)(Vt + (size_t)HID * SEQ);  // f32 [SEQ], pre-scaled
    float* out = (float*)d_out;

    // bf16 scratch carved from d_out (attn overwrites it at the very end)
    short* hsb = (short*)d_out;
    short* Wb  = hsb + (size_t)SEQ * HID;

    cast_all_kernel<<<dim3(2402), 256, 0, stream>>>(
        hs, Wq, Wk, Wv, mask, hsb, Wb, maskML);

    qkv_proj_kernel<<<dim3(HID / 128, SEQ / 128, 3), 256, 0, stream>>>(
        hsb, Wb, bq, bk, bv, Qb, Kb, Vt);

    attn_kernel<<<dim3(SEQ / KVB, NHEAD), 512, 0, stream>>>(Qb, Kb, Vt, maskML, out);
}